// Round 1
// baseline (181.704 us; speedup 1.0000x reference)
//
#include <hip/hip_runtime.h>
#include <stdint.h>

typedef __attribute__((ext_vector_type(8))) short short8;      // 8 x bf16 (MFMA A/B frag)
typedef __attribute__((ext_vector_type(4))) float f32x4;       // MFMA acc frag
typedef __attribute__((ext_vector_type(4))) float f4;
typedef __attribute__((ext_vector_type(4))) unsigned short us4;

typedef unsigned short ushort_t;

__device__ __forceinline__ ushort_t f2bf(float f) {
    union { float f; uint32_t u; } c; c.f = f;
    uint32_t u = c.u;
    uint32_t r = u + 0x7fffu + ((u >> 16) & 1u);   // RNE
    return (ushort_t)(r >> 16);
}
__device__ __forceinline__ float bf2f(ushort_t h) {
    union { uint32_t u; float f; } c; c.u = ((uint32_t)h) << 16;
    return c.f;
}

// ---------------------------------------------------------------------------
// Weight prep: transpose to B^T ([N][K]) layout, split into bf16 hi/lo.
// W1t = [gate_W | B_W]^T : [128][1024]; outWt : [1024][1024] (hi only);
// Ct = C_W^T : [1024][64] hi/lo.
// ---------------------------------------------------------------------------
__global__ void prep_weights(const float* __restrict__ gate_W, const float* __restrict__ B_W,
                             const float* __restrict__ C_W, const float* __restrict__ out_W,
                             ushort_t* __restrict__ W1t_hi, ushort_t* __restrict__ W1t_lo,
                             ushort_t* __restrict__ outWt,
                             ushort_t* __restrict__ Ct_hi, ushort_t* __restrict__ Ct_lo)
{
    int idx = blockIdx.x * 256 + threadIdx.x;
    int stride = gridDim.x * 256;
    for (int i = idx; i < 1024 * 1024; i += stride) {
        int nn = i >> 10, kk = i & 1023;
        outWt[i] = f2bf(out_W[kk * 1024 + nn]);
    }
    for (int i = idx; i < 128 * 1024; i += stride) {
        int nn = i >> 10, kk = i & 1023;
        float v = (nn < 64) ? gate_W[kk * 64 + nn] : B_W[kk * 64 + (nn - 64)];
        ushort_t h = f2bf(v);
        W1t_hi[i] = h;
        W1t_lo[i] = f2bf(v - bf2f(h));
    }
    for (int i = idx; i < 1024 * 64; i += stride) {
        int nn = i >> 6, kk = i & 63;
        float v = C_W[kk * 1024 + nn];
        ushort_t h = f2bf(v);
        Ct_hi[i] = h;
        Ct_lo[i] = f2bf(v - bf2f(h));
    }
}

// ---------------------------------------------------------------------------
// Generic MFMA GEMM: C[M][N] = A(fp32, split to bf16 hi/lo in staging) @ B^T
// (B pre-transposed bf16 hi/lo). Tile BM x 64, BK=64, 4 waves (2x2), each wave
// FM x 2 fragments of 16x16 (mfma_f32_16x16x32_bf16).
//   NPASS==3: acc += Ahi*Bhi + Alo*Bhi + Ahi*Blo  (~fp32 accuracy)
//   NPASS==1: acc += Ahi*Bhi                      (plain bf16)
// EPI: 1 = sigmoid(+gate_b) cols<64 -> gates_t[bn][s], cols>=64 -> b_t[bn][s]
//      2 = store fp32 to out0[m][N=1024]
//      3 = out0[m][n] = out1[m][n] * sigmoid(acc)
// ---------------------------------------------------------------------------
template <int FM, int NPASS, int EPI>
__global__ __launch_bounds__(256, 2)
void gemm_kernel(const float* __restrict__ Ap, int lda,
                 const ushort_t* __restrict__ Bhi, const ushort_t* __restrict__ Blo, int ldb,
                 int ktiles,
                 const float* __restrict__ gate_b,
                 float* __restrict__ out0, float* __restrict__ out1)
{
    constexpr int BM = FM * 32;     // 64 or 128
    __shared__ ushort_t As_hi[BM * 64];
    __shared__ ushort_t As_lo[(NPASS == 3) ? BM * 64 : 8];
    __shared__ ushort_t Bs_hi[64 * 64];
    __shared__ ushort_t Bs_lo[(NPASS == 3) ? 64 * 64 : 8];

    const int tid  = threadIdx.x;
    const int wave = tid >> 6;
    const int lane = tid & 63;
    const int wm = wave >> 1;           // 0..1
    const int wn = wave & 1;            // 0..1
    const int m0 = blockIdx.y * BM;
    const int n0 = blockIdx.x * 64;

    f32x4 acc[FM][2];
#pragma unroll
    for (int i = 0; i < FM; i++)
#pragma unroll
        for (int j = 0; j < 2; j++) {
            f32x4 z = {0.f, 0.f, 0.f, 0.f};
            acc[i][j] = z;
        }

    for (int kt = 0; kt < ktiles; ++kt) {
        const int k0 = kt * 64;
        __syncthreads();
        // --- stage A tile (fp32 -> bf16 hi/lo) ---
        {
            constexpr int F4PER = BM * 16 / 256;   // float4 chunks per thread
#pragma unroll
            for (int p = 0; p < F4PER; ++p) {
                int f = tid + p * 256;
                int row = f >> 4;
                int col = (f & 15) << 2;
                f4 v = *(const f4*)(Ap + (size_t)(m0 + row) * lda + k0 + col);
                us4 hi, lo;
#pragma unroll
                for (int j = 0; j < 4; j++) {
                    float xv = v[j];
                    ushort_t h = f2bf(xv);
                    hi[j] = h;
                    if (NPASS == 3) lo[j] = f2bf(xv - bf2f(h));
                }
                *(us4*)&As_hi[row * 64 + col] = hi;
                if (NPASS == 3) *(us4*)&As_lo[row * 64 + col] = lo;
            }
        }
        // --- stage B tile (bf16, already B^T [n][k]) ---
        {
#pragma unroll
            for (int p = 0; p < 2; ++p) {
                int c = tid + p * 256;
                int nrow = c >> 3;
                int col = (c & 7) << 3;
                *(short8*)&Bs_hi[nrow * 64 + col] =
                    *(const short8*)(Bhi + (size_t)(n0 + nrow) * ldb + k0 + col);
                if (NPASS == 3)
                    *(short8*)&Bs_lo[nrow * 64 + col] =
                        *(const short8*)(Blo + (size_t)(n0 + nrow) * ldb + k0 + col);
            }
        }
        __syncthreads();
        // --- fragments + MFMA ---
        short8 ah[FM][2], al[FM][2], bh[2][2], bl[2][2];
#pragma unroll
        for (int kk = 0; kk < 2; kk++) {
            int kb = kk * 32 + (lane >> 4) * 8;
#pragma unroll
            for (int fm = 0; fm < FM; fm++) {
                int r = wm * (FM * 16) + fm * 16 + (lane & 15);
                ah[fm][kk] = *(const short8*)&As_hi[r * 64 + kb];
                if (NPASS == 3) al[fm][kk] = *(const short8*)&As_lo[r * 64 + kb];
            }
#pragma unroll
            for (int fn = 0; fn < 2; fn++) {
                int r = wn * 32 + fn * 16 + (lane & 15);
                bh[fn][kk] = *(const short8*)&Bs_hi[r * 64 + kb];
                if (NPASS == 3) bl[fn][kk] = *(const short8*)&Bs_lo[r * 64 + kb];
            }
        }
#pragma unroll
        for (int fm = 0; fm < FM; fm++)
#pragma unroll
            for (int fn = 0; fn < 2; fn++)
#pragma unroll
                for (int kk = 0; kk < 2; kk++) {
                    acc[fm][fn] = __builtin_amdgcn_mfma_f32_16x16x32_bf16(
                        ah[fm][kk], bh[fn][kk], acc[fm][fn], 0, 0, 0);
                    if (NPASS == 3) {
                        acc[fm][fn] = __builtin_amdgcn_mfma_f32_16x16x32_bf16(
                            al[fm][kk], bh[fn][kk], acc[fm][fn], 0, 0, 0);
                        acc[fm][fn] = __builtin_amdgcn_mfma_f32_16x16x32_bf16(
                            ah[fm][kk], bl[fn][kk], acc[fm][fn], 0, 0, 0);
                    }
                }
    }

    // --- epilogue ---  C/D layout: col = lane&15, row = (lane>>4)*4 + reg
    const int mbase = m0 + wm * (FM * 16);
#pragma unroll
    for (int fm = 0; fm < FM; fm++) {
#pragma unroll
        for (int fn = 0; fn < 2; fn++) {
            int col = n0 + wn * 32 + fn * 16 + (lane & 15);
            int rb = mbase + fm * 16 + ((lane >> 4) << 2);
#pragma unroll
            for (int r = 0; r < 4; r++) {
                int m = rb + r;
                float v = acc[fm][fn][r];
                if (EPI == 1) {
                    int b = m >> 12, s = m & 4095;
                    if (col < 64) {
                        float g = 1.f / (1.f + __expf(-(v + gate_b[col])));
                        out0[((size_t)(b * 64 + col)) * 4096 + s] = g;
                    } else {
                        out1[((size_t)(b * 64 + col - 64)) * 4096 + s] = v;
                    }
                } else if (EPI == 2) {
                    out0[(size_t)m * 1024 + col] = v;
                } else {
                    float g = 1.f / (1.f + __expf(-v));
                    out0[(size_t)m * 1024 + col] = out1[(size_t)m * 1024 + col] * g;
                }
            }
        }
    }
}

// ---------------------------------------------------------------------------
// Scan: h_t = a_t * h_{t-1} + b_t per (batch,n) lane. One block per (b,n);
// thread-local 16-step segment + Hillis-Steele block scan of affine pairs.
// Inputs in [b*64+n][s] layout; output h in [m][n] (m = b*4096+s) for GEMM.
// ---------------------------------------------------------------------------
__global__ __launch_bounds__(256)
void scan_kernel(const float* __restrict__ gates, const float* __restrict__ bvals,
                 float* __restrict__ h_out)
{
    __shared__ float SA[256], SB[256];
    const int bn = blockIdx.x;          // 0..255
    const int t = threadIdx.x;
    const int b = bn >> 6, n = bn & 63;
    const size_t base = (size_t)bn * 4096 + (size_t)t * 16;

    float a[16], bb[16];
#pragma unroll
    for (int q = 0; q < 4; q++) {
        f4 va = *(const f4*)(gates + base + q * 4);
        f4 vb = *(const f4*)(bvals + base + q * 4);
#pragma unroll
        for (int j = 0; j < 4; j++) { a[q * 4 + j] = va[j]; bb[q * 4 + j] = vb[j]; }
    }
    float A = 1.f, Bv = 0.f;
#pragma unroll
    for (int i = 0; i < 16; i++) { Bv = a[i] * Bv + bb[i]; A *= a[i]; }
    SA[t] = A; SB[t] = Bv;
    __syncthreads();
    for (int off = 1; off < 256; off <<= 1) {
        float a1 = 1.f, b1 = 0.f;
        if (t >= off) { a1 = SA[t - off]; b1 = SB[t - off]; }
        float a2 = SA[t], b2 = SB[t];
        __syncthreads();
        SA[t] = a1 * a2;
        SB[t] = a2 * b1 + b2;
        __syncthreads();
    }
    float h = (t == 0) ? 0.f : SB[t - 1];
    size_t obase = ((size_t)b * 4096 + (size_t)t * 16) * 64 + n;
#pragma unroll
    for (int i = 0; i < 16; i++) {
        h = a[i] * h + bb[i];
        h_out[obase + (size_t)i * 64] = h;
    }
}

// ---------------------------------------------------------------------------
extern "C" void kernel_launch(void* const* d_in, const int* in_sizes, int n_in,
                              void* d_out, int out_size, void* d_ws, size_t ws_size,
                              hipStream_t stream)
{
    const float* x      = (const float*)d_in[0];   // (4,4096,1024)
    const float* gate_W = (const float*)d_in[1];   // (1024,64)
    const float* gate_b = (const float*)d_in[2];   // (64,)
    const float* B_W    = (const float*)d_in[3];   // (1024,64)
    const float* C_W    = (const float*)d_in[4];   // (64,1024)
    const float* out_W  = (const float*)d_in[5];   // (1024,1024)
    // d_in[6] mix_weight: cancels algebraically (h_next == h_final). unused.
    // d_in[7] chunk_size: S % C == 0 path. unused.
    float* out = (float*)d_out;

    char* ws = (char*)d_ws;
    float*    gates  = (float*)(ws + 0);            //  4 MiB  [256][4096]
    float*    bvals  = (float*)(ws + 4194304);      //  4 MiB
    float*    hbuf   = (float*)(ws + 8388608);      //  4 MiB  [16384][64]
    float*    ybuf   = (float*)(ws + 12582912);     // 64 MiB  [16384][1024]
    ushort_t* W1t_hi = (ushort_t*)(ws + 79691776);  // [128][1024]
    ushort_t* W1t_lo = (ushort_t*)(ws + 79953920);
    ushort_t* outWt  = (ushort_t*)(ws + 80216064);  // [1024][1024]
    ushort_t* Ct_hi  = (ushort_t*)(ws + 82313216);  // [1024][64]
    ushort_t* Ct_lo  = (ushort_t*)(ws + 82444288);

    prep_weights<<<1024, 256, 0, stream>>>(gate_W, B_W, C_W, out_W,
                                           W1t_hi, W1t_lo, outWt, Ct_hi, Ct_lo);

    // P1: Z = x @ [gate_W | B_W] (split precision) -> gates, bvals (transposed)
    gemm_kernel<2, 3, 1><<<dim3(2, 256), 256, 0, stream>>>(
        x, 1024, W1t_hi, W1t_lo, 1024, 16, gate_b, gates, bvals);

    scan_kernel<<<256, 256, 0, stream>>>(gates, bvals, hbuf);

    // D1: y = h @ C_W (split precision)
    gemm_kernel<2, 3, 2><<<dim3(16, 256), 256, 0, stream>>>(
        hbuf, 64, Ct_hi, Ct_lo, 64, 1, nullptr, ybuf, nullptr);

    // D2: out = y * sigmoid(x @ out_W) (bf16)
    gemm_kernel<4, 1, 3><<<dim3(16, 128), 256, 0, stream>>>(
        x, 1024, outWt, nullptr, 1024, 16, nullptr, out, ybuf);
}

// Round 2
// 108.648 us; speedup vs baseline: 1.6724x; 1.6724x over previous
//
#include <hip/hip_runtime.h>
#include <stdint.h>

typedef __attribute__((ext_vector_type(8))) short short8;      // 8 x bf16 (MFMA A/B frag)
typedef __attribute__((ext_vector_type(4))) float f32x4;       // MFMA acc frag
typedef __attribute__((ext_vector_type(4))) float f4;
typedef __attribute__((ext_vector_type(4))) unsigned short us4;

typedef unsigned short ushort_t;

__device__ __forceinline__ ushort_t f2bf(float f) {
    union { float f; uint32_t u; } c; c.f = f;
    uint32_t u = c.u;
    uint32_t r = u + 0x7fffu + ((u >> 16) & 1u);   // RNE
    return (ushort_t)(r >> 16);
}
__device__ __forceinline__ float bf2f(ushort_t h) {
    union { uint32_t u; float f; } c; c.u = ((uint32_t)h) << 16;
    return c.f;
}

// async global->LDS, 16B per lane; LDS dest = wave-uniform base + lane*16
typedef const __attribute__((address_space(1))) unsigned int as1_uint;
typedef __attribute__((address_space(3))) unsigned int as3_uint;
__device__ __forceinline__ void gload_lds16(const void* g, void* l) {
    __builtin_amdgcn_global_load_lds((as1_uint*)g, (as3_uint*)l, 16, 0, 0);
}

// ---------------------------------------------------------------------------
// Weight prep: B^T ([N][K]) layouts.
// W1t = [gate_W | B_W]^T : [128][1024] hi/lo; outWt : [1024][1024] hi only;
// Ct = C_W^T : [1024][64] hi only.
// ---------------------------------------------------------------------------
__global__ void prep_weights(const float* __restrict__ gate_W, const float* __restrict__ B_W,
                             const float* __restrict__ C_W, const float* __restrict__ out_W,
                             ushort_t* __restrict__ W1t_hi, ushort_t* __restrict__ W1t_lo,
                             ushort_t* __restrict__ outWt, ushort_t* __restrict__ Ct)
{
    int idx = blockIdx.x * 256 + threadIdx.x;
    int stride = gridDim.x * 256;
    for (int i = idx; i < 1024 * 1024; i += stride) {
        int nn = i >> 10, kk = i & 1023;
        outWt[i] = f2bf(out_W[kk * 1024 + nn]);
    }
    for (int i = idx; i < 128 * 1024; i += stride) {
        int nn = i >> 10, kk = i & 1023;
        float v = (nn < 64) ? gate_W[kk * 64 + nn] : B_W[kk * 64 + (nn - 64)];
        ushort_t h = f2bf(v);
        W1t_hi[i] = h;
        W1t_lo[i] = f2bf(v - bf2f(h));
    }
    for (int i = idx; i < 1024 * 64; i += stride) {
        int nn = i >> 6, kk = i & 63;
        Ct[i] = f2bf(C_W[kk * 1024 + nn]);
    }
}

// ---------------------------------------------------------------------------
// P1: Z^T[n][s] = sum_k W1[k][n] * x[s][k], split precision (3-pass bf16),
// split-K (2 chunks of 512). A = W1t (bf16 hi/lo, global_load_lds),
// B = x (fp32, reg-staged -> hi/lo; hi also written out as x_hi).
// Output: Zpart[kc][b*128 + n][s] fp32 (raw, pre-sigmoid/bias).
// Tile: 128(n) x 64(s), BK=64, 4 waves 2x2 (wave = 64n x 32s, FM=4, FN=2).
// ---------------------------------------------------------------------------
__global__ __launch_bounds__(256, 2)
void p1_kernel(const float* __restrict__ x,
               const ushort_t* __restrict__ W1t_hi, const ushort_t* __restrict__ W1t_lo,
               ushort_t* __restrict__ x_hi, float* __restrict__ Zpart)
{
    __shared__ ushort_t Ash[128 * 64];
    __shared__ ushort_t Asl[128 * 64];
    __shared__ ushort_t Bsh[64 * 64];
    __shared__ ushort_t Bsl[64 * 64];

    const int tid = threadIdx.x;
    const int wave = tid >> 6, lane = tid & 63;
    const int wm = wave >> 1, wn = wave & 1;
    const int s0 = blockIdx.x * 64;
    const int kc = blockIdx.y;

    f32x4 acc[4][2];
#pragma unroll
    for (int i = 0; i < 4; i++)
#pragma unroll
        for (int j = 0; j < 2; j++) { f32x4 z = {0.f,0.f,0.f,0.f}; acc[i][j] = z; }

    for (int kt = 0; kt < 8; ++kt) {
        const int k0 = kc * 512 + kt * 64;
        // A (W1t hi/lo) via global_load_lds: [128][64] bf16 = 1024 x 16B chunks
#pragma unroll
        for (int p = 0; p < 4; ++p) {
            int c = p * 256 + wave * 64 + lane;
            int row = c >> 3, col = (c & 7) * 8;
            gload_lds16(W1t_hi + (size_t)row * 1024 + k0 + col,
                        &Ash[(p * 256 + wave * 64) * 8]);
            gload_lds16(W1t_lo + (size_t)row * 1024 + k0 + col,
                        &Asl[(p * 256 + wave * 64) * 8]);
        }
        // B (x fp32 -> hi/lo), write x_hi as byproduct
#pragma unroll
        for (int p = 0; p < 4; ++p) {
            int f = tid + p * 256;           // 1024 chunks of 4 floats
            int row = f >> 4, col = (f & 15) * 4;
            f4 v = *(const f4*)(x + (size_t)(s0 + row) * 1024 + k0 + col);
            us4 hi, lo;
#pragma unroll
            for (int j = 0; j < 4; j++) {
                ushort_t h = f2bf(v[j]);
                hi[j] = h;
                lo[j] = f2bf(v[j] - bf2f(h));
            }
            *(us4*)&Bsh[row * 64 + col] = hi;
            *(us4*)&Bsl[row * 64 + col] = lo;
            *(us4*)(x_hi + (size_t)(s0 + row) * 1024 + k0 + col) = hi;
        }
        __syncthreads();
#pragma unroll
        for (int kk = 0; kk < 2; ++kk) {
            const int kb = kk * 32 + (lane >> 4) * 8;
            short8 ah[4], al[4], bh[2], bl[2];
#pragma unroll
            for (int fm = 0; fm < 4; fm++) {
                int r = wm * 64 + fm * 16 + (lane & 15);
                ah[fm] = *(const short8*)&Ash[r * 64 + kb];
                al[fm] = *(const short8*)&Asl[r * 64 + kb];
            }
#pragma unroll
            for (int fn = 0; fn < 2; fn++) {
                int r = wn * 32 + fn * 16 + (lane & 15);
                bh[fn] = *(const short8*)&Bsh[r * 64 + kb];
                bl[fn] = *(const short8*)&Bsl[r * 64 + kb];
            }
#pragma unroll
            for (int fm = 0; fm < 4; fm++)
#pragma unroll
                for (int fn = 0; fn < 2; fn++) {
                    acc[fm][fn] = __builtin_amdgcn_mfma_f32_16x16x32_bf16(ah[fm], bh[fn], acc[fm][fn], 0, 0, 0);
                    acc[fm][fn] = __builtin_amdgcn_mfma_f32_16x16x32_bf16(al[fm], bh[fn], acc[fm][fn], 0, 0, 0);
                    acc[fm][fn] = __builtin_amdgcn_mfma_f32_16x16x32_bf16(ah[fm], bl[fn], acc[fm][fn], 0, 0, 0);
                }
        }
        __syncthreads();
    }
    // epilogue: Zpart[kc*512 + b*128 + nrow][sb], coalesced in s
#pragma unroll
    for (int fm = 0; fm < 4; fm++) {
#pragma unroll
        for (int fn = 0; fn < 2; fn++) {
            int scol = s0 + wn * 32 + fn * 16 + (lane & 15);
            int b = scol >> 12, sb = scol & 4095;
            int nbase = wm * 64 + fm * 16 + ((lane >> 4) << 2);
#pragma unroll
            for (int r = 0; r < 4; r++) {
                Zpart[((size_t)kc * 512 + b * 128 + nbase + r) * 4096 + sb] = acc[fm][fn][r];
            }
        }
    }
}

// ---------------------------------------------------------------------------
// Scan: combine split-K partials, gate = sigmoid(zg+bias), b = zb;
// h_t = a_t*h + b_t. One block per (b,n). Output hT[b*64+n][s] bf16.
// ---------------------------------------------------------------------------
__global__ __launch_bounds__(256)
void scan_kernel(const float* __restrict__ Zpart, const float* __restrict__ gate_b,
                 ushort_t* __restrict__ hT)
{
    __shared__ float SA[256], SB[256];
    const int bn = blockIdx.x;          // 0..255
    const int t = threadIdx.x;
    const int b = bn >> 6, n = bn & 63;
    const float gb = gate_b[n];
    const float* g0 = Zpart + ((size_t)(b * 128 + n)) * 4096;
    const float* g1 = g0 + (size_t)512 * 4096;
    const float* b0 = Zpart + ((size_t)(b * 128 + 64 + n)) * 4096;
    const float* b1 = b0 + (size_t)512 * 4096;
    const int sb = t * 16;

    float a[16], bb[16];
#pragma unroll
    for (int q = 0; q < 4; q++) {
        f4 vg0 = *(const f4*)(g0 + sb + q * 4);
        f4 vg1 = *(const f4*)(g1 + sb + q * 4);
        f4 vb0 = *(const f4*)(b0 + sb + q * 4);
        f4 vb1 = *(const f4*)(b1 + sb + q * 4);
#pragma unroll
        for (int j = 0; j < 4; j++) {
            a[q * 4 + j] = 1.f / (1.f + __expf(-(vg0[j] + vg1[j] + gb)));
            bb[q * 4 + j] = vb0[j] + vb1[j];
        }
    }
    float A = 1.f, Bv = 0.f;
#pragma unroll
    for (int i = 0; i < 16; i++) { Bv = a[i] * Bv + bb[i]; A *= a[i]; }
    SA[t] = A; SB[t] = Bv;
    __syncthreads();
    for (int off = 1; off < 256; off <<= 1) {
        float a1 = 1.f, b1v = 0.f;
        if (t >= off) { a1 = SA[t - off]; b1v = SB[t - off]; }
        float a2 = SA[t], b2 = SB[t];
        __syncthreads();
        SA[t] = a1 * a2;
        SB[t] = a2 * b1v + b2;
        __syncthreads();
    }
    float h = (t == 0) ? 0.f : SB[t - 1];
    ushort_t ov[16];
#pragma unroll
    for (int i = 0; i < 16; i++) {
        h = a[i] * h + bb[i];
        ov[i] = f2bf(h);
    }
    ushort_t* dst = hT + (size_t)bn * 4096 + sb;
#pragma unroll
    for (int q = 0; q < 4; q++) {
        us4 o; o[0]=ov[q*4]; o[1]=ov[q*4+1]; o[2]=ov[q*4+2]; o[3]=ov[q*4+3];
        *(us4*)(dst + q * 4) = o;
    }
}

// ---------------------------------------------------------------------------
// Fused D1+D2: out[m][n] = (h @ C_W)[m][n] * sigmoid((x @ out_W)[m][n]).
// 128x128 tile, BK=64, 4 waves 2x2 (wave 64x64, 4x4 frags).
// y-phase: As <- transpose(hT tile) (reg-staged), Bs <- Ct (gload_lds), K=64.
// main: As <- x_hi, Bs <- outWt, both gload_lds, K=1024.
// ---------------------------------------------------------------------------
__global__ __launch_bounds__(256, 2)
void fused_kernel(const ushort_t* __restrict__ x_hi, const ushort_t* __restrict__ outWt,
                  const ushort_t* __restrict__ hT, const ushort_t* __restrict__ Ct,
                  float* __restrict__ out)
{
    __shared__ ushort_t As[128 * 64];
    __shared__ ushort_t Bs[128 * 64];

    const int tid = threadIdx.x;
    const int wave = tid >> 6, lane = tid & 63;
    const int wm = wave >> 1, wn = wave & 1;

    // XCD-bijective swizzle: nwg=1024 divisible by 8
    const int flat = blockIdx.x;
    const int swz = (flat & 7) * 128 + (flat >> 3);
    const int m0 = (swz >> 3) * 128;
    const int n0 = (swz & 7) * 128;

    f32x4 acc_g[4][4], acc_y[4][4];
#pragma unroll
    for (int i = 0; i < 4; i++)
#pragma unroll
        for (int j = 0; j < 4; j++) {
            f32x4 z = {0.f,0.f,0.f,0.f};
            acc_g[i][j] = z; acc_y[i][j] = z;
        }

    // ---------- y phase (K = 64, k index = SSM state n) ----------
    {
        const int b64 = (m0 >> 12) * 64;
        const int sb0 = m0 & 4095;
        // Bs <- Ct[n0+row][col], 1024 chunks
#pragma unroll
        for (int p = 0; p < 4; ++p) {
            int c = p * 256 + wave * 64 + lane;
            gload_lds16(Ct + (size_t)(n0 + (c >> 3)) * 64 + (c & 7) * 8,
                        &Bs[(p * 256 + wave * 64) * 8]);
        }
        // As <- transpose of hT: As[m_local][kn] = h[m0+m_local][kn]
#pragma unroll
        for (int p = 0; p < 4; ++p) {
            int c = tid + p * 256;           // kn = c>>4, mchunk = c&15
            int kn = c >> 4, mc = c & 15;
            short8 v = *(const short8*)(hT + (size_t)(b64 + kn) * 4096 + sb0 + mc * 8);
#pragma unroll
            for (int j = 0; j < 8; ++j)
                As[(mc * 8 + j) * 64 + kn] = (ushort_t)v[j];
        }
        __syncthreads();
#pragma unroll
        for (int kk = 0; kk < 2; ++kk) {
            const int kb = kk * 32 + (lane >> 4) * 8;
            short8 af[4], bf[4];
#pragma unroll
            for (int fm = 0; fm < 4; fm++)
                af[fm] = *(const short8*)&As[(wm * 64 + fm * 16 + (lane & 15)) * 64 + kb];
#pragma unroll
            for (int fn = 0; fn < 4; fn++)
                bf[fn] = *(const short8*)&Bs[(wn * 64 + fn * 16 + (lane & 15)) * 64 + kb];
#pragma unroll
            for (int fm = 0; fm < 4; fm++)
#pragma unroll
                for (int fn = 0; fn < 4; fn++)
                    acc_y[fm][fn] = __builtin_amdgcn_mfma_f32_16x16x32_bf16(af[fm], bf[fn], acc_y[fm][fn], 0, 0, 0);
        }
        __syncthreads();
    }

    // ---------- main loop: x_hi @ outWt^T, K = 1024 ----------
    for (int kt = 0; kt < 16; ++kt) {
        const int k0 = kt * 64;
#pragma unroll
        for (int p = 0; p < 4; ++p) {
            int c = p * 256 + wave * 64 + lane;
            int row = c >> 3, col = (c & 7) * 8;
            gload_lds16(x_hi + (size_t)(m0 + row) * 1024 + k0 + col,
                        &As[(p * 256 + wave * 64) * 8]);
            gload_lds16(outWt + (size_t)(n0 + row) * 1024 + k0 + col,
                        &Bs[(p * 256 + wave * 64) * 8]);
        }
        __syncthreads();
#pragma unroll
        for (int kk = 0; kk < 2; ++kk) {
            const int kb = kk * 32 + (lane >> 4) * 8;
            short8 af[4], bf[4];
#pragma unroll
            for (int fm = 0; fm < 4; fm++)
                af[fm] = *(const short8*)&As[(wm * 64 + fm * 16 + (lane & 15)) * 64 + kb];
#pragma unroll
            for (int fn = 0; fn < 4; fn++)
                bf[fn] = *(const short8*)&Bs[(wn * 64 + fn * 16 + (lane & 15)) * 64 + kb];
#pragma unroll
            for (int fm = 0; fm < 4; fm++)
#pragma unroll
                for (int fn = 0; fn < 4; fn++)
                    acc_g[fm][fn] = __builtin_amdgcn_mfma_f32_16x16x32_bf16(af[fm], bf[fn], acc_g[fm][fn], 0, 0, 0);
        }
        __syncthreads();
    }

    // ---------- epilogue: out = acc_y * sigmoid(acc_g) ----------
#pragma unroll
    for (int fm = 0; fm < 4; fm++) {
#pragma unroll
        for (int fn = 0; fn < 4; fn++) {
            int col = n0 + wn * 64 + fn * 16 + (lane & 15);
            int rbase = m0 + wm * 64 + fm * 16 + ((lane >> 4) << 2);
#pragma unroll
            for (int r = 0; r < 4; r++) {
                float og = 1.f / (1.f + __expf(-acc_g[fm][fn][r]));
                out[(size_t)(rbase + r) * 1024 + col] = acc_y[fm][fn][r] * og;
            }
        }
    }
}

// ---------------------------------------------------------------------------
extern "C" void kernel_launch(void* const* d_in, const int* in_sizes, int n_in,
                              void* d_out, int out_size, void* d_ws, size_t ws_size,
                              hipStream_t stream)
{
    const float* x      = (const float*)d_in[0];   // (4,4096,1024)
    const float* gate_W = (const float*)d_in[1];   // (1024,64)
    const float* gate_b = (const float*)d_in[2];   // (64,)
    const float* B_W    = (const float*)d_in[3];   // (1024,64)
    const float* C_W    = (const float*)d_in[4];   // (64,1024)
    const float* out_W  = (const float*)d_in[5];   // (1024,1024)
    // d_in[6] mix_weight cancels (h_next == h_final); d_in[7] chunk_size unused.
    float* out = (float*)d_out;

    char* ws = (char*)d_ws;
    float*    Zpart  = (float*)(ws + 0);            // 16 MiB  [2][512][4096]
    ushort_t* hT     = (ushort_t*)(ws + 16777216);  //  2 MiB  [256][4096]
    ushort_t* x_hi   = (ushort_t*)(ws + 18874368);  // 32 MiB  [16384][1024]
    ushort_t* W1t_hi = (ushort_t*)(ws + 52428800);  // [128][1024]
    ushort_t* W1t_lo = (ushort_t*)(ws + 52690944);
    ushort_t* outWt  = (ushort_t*)(ws + 52953088);  // [1024][1024]
    ushort_t* Ct     = (ushort_t*)(ws + 55050240);  // [1024][64]

    prep_weights<<<512, 256, 0, stream>>>(gate_W, B_W, C_W, out_W,
                                          W1t_hi, W1t_lo, outWt, Ct);

    p1_kernel<<<dim3(256, 2), 256, 0, stream>>>(x, W1t_hi, W1t_lo, x_hi, Zpart);

    scan_kernel<<<256, 256, 0, stream>>>(Zpart, gate_b, hT);

    fused_kernel<<<1024, 256, 0, stream>>>(x_hi, outWt, hT, Ct, out);
}